// Round 2
// baseline (1569.572 us; speedup 1.0000x reference)
//
#include <hip/hip_runtime.h>

#define SPATIAL 32768
#define BATCH   4
#define CH      256
#define KCODES  1024
#define NPTS    (BATCH*SPATIAL)          // 131072
#define ZQ_SIZE (BATCH*CH*SPATIAL)       // 33554432

// workspace layout (bytes)
#define WS_LOSS  0        // double
#define WS_ENORM 16       // float[1024]
#define WS_IDX   4112     // int[NPTS]

// en_np[k] = fp32(||e_k||^2) via f64 accumulation (within 1 ulp of numpy's
// fp32 pairwise sum; en ~ 8e-5 so a 1-ulp (~1e-11) difference flips the
// fl(zn+en) rounding with P~3e-7 per relevant pair -> negligible)
__global__ __launch_bounds__(256) void vq_enorm(const float* __restrict__ emb,
                                                float* __restrict__ enorm) {
  int k = blockIdx.x * 256 + threadIdx.x;
  const float* e = emb + (size_t)k * CH;
  double s = 0.0;
#pragma unroll 8
  for (int c = 0; c < CH; ++c) s += (double)e[c] * (double)e[c];
  enorm[k] = (float)s;
}

// 1024 blocks x 256 threads; block = 128 points x all 1024 codes.
// Replicates numpy fp32: d = fl(fl(zn + en) - 2*g), g = ascending-c fmaf
// chain (matches BLAS sgemm k-loop); argmin with first-index tie-break.
__global__ __launch_bounds__(256) void vq_main(
    const float* __restrict__ z, const float* __restrict__ emb,
    const float* __restrict__ enorm, float* __restrict__ out_idx,
    int* __restrict__ idx_i, double* __restrict__ loss_acc) {
  __shared__ float zbuf[32][132];
  __shared__ float ebuf[32][132];
  __shared__ float znb[128];
  __shared__ float rm1[128];
  __shared__ int   ri1[128];

  int tid = threadIdx.x;
  int n0 = blockIdx.x * 128;
  int b  = n0 / SPATIAL;
  int s0 = n0 % SPATIAL;
  const float* zb_base = z + (size_t)b * CH * SPATIAL + s0;

  if (tid < 128) {
    rm1[tid] = 1e30f; ri1[tid] = 0;
    // zn in f64 -> f32: same binade as numpy's fp32 zn, differs by a
    // multiple of its ulp -> uniform translation of all d_k -> argmin-safe
    double s = 0.0;
#pragma unroll 8
    for (int c = 0; c < CH; ++c) {
      float v = zb_base[(size_t)c * SPATIAL + tid];
      s += (double)v * (double)v;
    }
    znb[tid] = (float)s;
  }

  int tn = tid >> 4;   // 0..15 -> 8 points each
  int tk = tid & 15;   // 0..15 -> 8 codes each

  for (int kt = 0; kt < KCODES / 128; ++kt) {
    int k0 = kt * 128;
    float acc[8][8];
#pragma unroll
    for (int i = 0; i < 8; ++i)
#pragma unroll
      for (int j = 0; j < 8; ++j) acc[i][j] = 0.f;

    for (int cc = 0; cc < 8; ++cc) {
      int c0 = cc * 32;
      __syncthreads();
#pragma unroll
      for (int j = 0; j < 16; ++j) {
        int e = tid + j * 256;
        zbuf[e >> 7][e & 127] =
            zb_base[(size_t)(c0 + (e >> 7)) * SPATIAL + (e & 127)];
      }
#pragma unroll
      for (int j = 0; j < 16; ++j) {
        int e = tid + j * 256;
        ebuf[e & 31][e >> 5] = emb[(size_t)(k0 + (e >> 5)) * CH + c0 + (e & 31)];
      }
      __syncthreads();
      // ascending c, one fmaf chain per acc element (bit-matches BLAS)
#pragma unroll 2
      for (int c = 0; c < 32; ++c) {
        float4 za  = *reinterpret_cast<float4*>(&zbuf[c][tn * 8]);
        float4 zb2 = *reinterpret_cast<float4*>(&zbuf[c][tn * 8 + 4]);
        float4 ea  = *reinterpret_cast<float4*>(&ebuf[c][tk * 8]);
        float4 eb2 = *reinterpret_cast<float4*>(&ebuf[c][tk * 8 + 4]);
        float zr[8] = {za.x, za.y, za.z, za.w, zb2.x, zb2.y, zb2.z, zb2.w};
        float er[8] = {ea.x, ea.y, ea.z, ea.w, eb2.x, eb2.y, eb2.z, eb2.w};
#pragma unroll
        for (int i = 0; i < 8; ++i)
#pragma unroll
          for (int j = 0; j < 8; ++j)
            acc[i][j] = fmaf(zr[i], er[j], acc[i][j]);
      }
    }

    // fold this k-tile into running argmin with numpy fp32 rounding
    float4 en0 = *reinterpret_cast<const float4*>(&enorm[k0 + tk * 8]);
    float4 en1 = *reinterpret_cast<const float4*>(&enorm[k0 + tk * 8 + 4]);
    float en[8] = {en0.x, en0.y, en0.z, en0.w, en1.x, en1.y, en1.z, en1.w};
#pragma unroll
    for (int i = 0; i < 8; ++i) {
      float zn_i = znb[tn * 8 + i];
      float m1 = 1e30f;
      int i1 = 0x7fffffff;
#pragma unroll
      for (int j = 0; j < 8; ++j) {
        float t1 = zn_i + en[j];            // fl(zn + en)   [no contraction possible]
        float sc = t1 - 2.f * acc[i][j];    // fl(t1 - 2g)   [2g exact -> fma-safe]
        int gk = k0 + tk * 8 + j;
        if (sc < m1) { m1 = sc; i1 = gk; }  // strict < keeps lowest index
      }
      // reduce across the 16 tk-threads (lanes differ only in tk bits)
#pragma unroll
      for (int m = 1; m <= 8; m <<= 1) {
        float om1 = __shfl_xor(m1, m);
        int   oi1 = __shfl_xor(i1, m);
        if (om1 < m1 || (om1 == m1 && oi1 < i1)) { m1 = om1; i1 = oi1; }
      }
      if (tk == 0) {
        int nl = tn * 8 + i;   // exclusive writer per row
        if (m1 < rm1[nl]) { rm1[nl] = m1; ri1[nl] = i1; }  // equal keeps earlier k
      }
    }
  }

  __syncthreads();
  double dv = 0.0;
  if (tid < 128) {
    int n = n0 + tid;
    out_idx[n] = (float)ri1[tid];
    idx_i[n] = ri1[tid];
    dv = (double)rm1[tid];       // full ||z-e||^2 (zn included in score)
  }
#pragma unroll
  for (int m = 1; m < 64; m <<= 1) dv += __shfl_xor(dv, m);
  if ((tid & 63) == 0) atomicAdd(loss_acc, dv);
}

// z_q[b][c][s] = emb[idx[b*S+s]][c]; also finalize loss
__global__ __launch_bounds__(256) void vq_scatter(
    const float* __restrict__ emb, const int* __restrict__ idx_i,
    float* __restrict__ zq, const double* __restrict__ loss_acc,
    float* __restrict__ loss_out) {
  int c = blockIdx.y, b = blockIdx.z;
  int s = (blockIdx.x * 256 + threadIdx.x) * 4;
  int nb = b * SPATIAL + s;
  int4 iv = *reinterpret_cast<const int4*>(&idx_i[nb]);
  float4 o;
  o.x = emb[(size_t)iv.x * CH + c];
  o.y = emb[(size_t)iv.y * CH + c];
  o.z = emb[(size_t)iv.z * CH + c];
  o.w = emb[(size_t)iv.w * CH + c];
  *reinterpret_cast<float4*>(&zq[((size_t)(b * CH + c)) * SPATIAL + s]) = o;
  if (blockIdx.x == 0 && blockIdx.y == 0 && blockIdx.z == 0 && threadIdx.x == 0)
    loss_out[0] = (float)(loss_acc[0] * 1.25 / (double)ZQ_SIZE);
}

extern "C" void kernel_launch(void* const* d_in, const int* in_sizes, int n_in,
                              void* d_out, int out_size, void* d_ws, size_t ws_size,
                              hipStream_t stream) {
  const float* z   = (const float*)d_in[0];
  const float* emb = (const float*)d_in[1];
  float* out = (float*)d_out;
  char* ws = (char*)d_ws;

  double* loss_acc = (double*)(ws + WS_LOSS);
  float*  enorm    = (float*)(ws + WS_ENORM);
  int*    idx_i    = (int*)(ws + WS_IDX);

  float* loss_out = out + ZQ_SIZE;
  float* out_idx  = out + ZQ_SIZE + 1;

  hipMemsetAsync(d_ws, 0, 16, stream);
  vq_enorm<<<KCODES / 256, 256, 0, stream>>>(emb, enorm);
  vq_main<<<NPTS / 128, 256, 0, stream>>>(z, emb, enorm, out_idx, idx_i,
                                          loss_acc);
  vq_scatter<<<dim3(SPATIAL / 1024, CH, BATCH), 256, 0, stream>>>(
      emb, idx_i, out, loss_acc, loss_out);
}

// Round 3
// 772.984 us; speedup vs baseline: 2.0305x; 2.0305x over previous
//
#include <hip/hip_runtime.h>

#define SPATIAL 32768
#define BATCH   4
#define CH      256
#define KCODES  1024
#define NPTS    (BATCH*SPATIAL)          // 131072
#define ZQ_SIZE (BATCH*CH*SPATIAL)       // 33554432

// workspace layout (bytes)
#define WS_LOSS  0                        // double
#define WS_CNT   8                        // int
#define WS_ENORM 16                       // float[1024]
#define WS_EH    4112                     // _Float16[1024*256]
#define WS_EL    (WS_EH + KCODES*CH*2)
#define WS_FLAGS (WS_EL + KCODES*CH*2)    // int[NPTS]

#define MARG 1e-4f   // flag margin: > 2*ulp(512) + worst split error

typedef _Float16 f16x8 __attribute__((ext_vector_type(8)));
typedef float    f32x4 __attribute__((ext_vector_type(4)));
typedef int      i32x4 __attribute__((ext_vector_type(4)));

// split e*1024 into f16 hi/lo (scale keeps lo in normal f16 range)
__global__ __launch_bounds__(256) void vq_prep(const float* __restrict__ emb,
                                               _Float16* __restrict__ eh,
                                               _Float16* __restrict__ el) {
  int i = blockIdx.x * 256 + threadIdx.x;
  float es = emb[i] * 1024.0f;
  _Float16 h = (_Float16)es;
  eh[i] = h;
  el[i] = (_Float16)(es - (float)h);
}

__global__ __launch_bounds__(256) void vq_enorm(const float* __restrict__ emb,
                                                float* __restrict__ enorm) {
  int k = blockIdx.x * 256 + threadIdx.x;
  const float* e = emb + (size_t)k * CH;
  double s = 0.0;
#pragma unroll 8
  for (int c = 0; c < CH; ++c) s = fma((double)e[c], (double)e[c], s);
  enorm[k] = (float)s;
}

// 2048 blocks x 256 thr; block = 64 points x all 1024 codes via f16-split MFMA
__global__ __launch_bounds__(256) void vq_main(
    const float* __restrict__ z, const _Float16* __restrict__ eh_g,
    const _Float16* __restrict__ el_g, const float* __restrict__ enorm,
    float* __restrict__ out_idx, double* __restrict__ loss_acc,
    int* __restrict__ flag_cnt, int* __restrict__ flags) {
  __shared__ _Float16 zh[64][258];   // pad 258: write banks 2-way (free)
  __shared__ _Float16 zl[64][258];
  __shared__ float en_s[KCODES];
  __shared__ float znb[64];
  __shared__ float rm1[4][64];
  __shared__ float rm2[4][64];
  __shared__ int   ri1[4][64];

  int tid = threadIdx.x;
  int w = tid >> 6;          // wave 0..3
  int lane = tid & 63;
  int n0 = blockIdx.x * 64;
  int b = n0 / SPATIAL, s0 = n0 % SPATIAL;
  const float* zb = z + (size_t)b * CH * SPATIAL + s0;

  // stage all of z for this block as f16 hi/lo (once, coalesced)
  {
    int pt = tid & 63, crow = tid >> 6;
#pragma unroll 4
    for (int j = 0; j < 64; ++j) {
      int c = crow + 4 * j;
      float v = zb[(size_t)c * SPATIAL + pt];
      _Float16 h = (_Float16)v;
      zh[pt][c] = h;
      zl[pt][c] = (_Float16)(v - (float)h);
    }
  }
#pragma unroll
  for (int j = 0; j < 4; ++j) en_s[tid + 256 * j] = enorm[tid + 256 * j];
  rm1[tid >> 6][tid & 63] = 1e30f;
  rm2[tid >> 6][tid & 63] = 1e30f;
  ri1[tid >> 6][tid & 63] = 0;
  if (tid < 64) {
    double s = 0.0;
    for (int c = 0; c < CH; ++c) {
      float v = zb[(size_t)c * SPATIAL + tid];
      s = fma((double)v, (double)v, s);
    }
    znb[tid] = (float)s;
  }
  __syncthreads();

  int hq = lane >> 4;   // 0..3  (k-slice group)
  int lr = lane & 15;   // A-row / B-col selector

  for (int kt = 0; kt < 8; ++kt) {
    int k0 = kt * 128;
    f32x4 acc[4][2];
#pragma unroll
    for (int m = 0; m < 4; ++m)
#pragma unroll
      for (int n = 0; n < 2; ++n) acc[m][n] = (f32x4){0.f, 0.f, 0.f, 0.f};

#pragma unroll 2
    for (int cc = 0; cc < 8; ++cc) {
      int ca = cc * 32 + hq * 8;
      f16x8 ah[4], al[4], bh[2], bl[2];
#pragma unroll
      for (int m = 0; m < 4; ++m) {
        const int* ph = (const int*)&zh[m * 16 + lr][ca];
        const int* pl = (const int*)&zl[m * 16 + lr][ca];
        i32x4 th = {ph[0], ph[1], ph[2], ph[3]};
        i32x4 tl = {pl[0], pl[1], pl[2], pl[3]};
        ah[m] = __builtin_bit_cast(f16x8, th);
        al[m] = __builtin_bit_cast(f16x8, tl);
      }
#pragma unroll
      for (int n = 0; n < 2; ++n) {
        int code = k0 + w * 32 + n * 16 + lr;
        bh[n] = *(const f16x8*)&eh_g[(size_t)code * CH + ca];
        bl[n] = *(const f16x8*)&el_g[(size_t)code * CH + ca];
      }
#pragma unroll
      for (int m = 0; m < 4; ++m)
#pragma unroll
        for (int n = 0; n < 2; ++n) {
          acc[m][n] = __builtin_amdgcn_mfma_f32_16x16x32_f16(ah[m], bh[n], acc[m][n], 0, 0, 0);
          acc[m][n] = __builtin_amdgcn_mfma_f32_16x16x32_f16(al[m], bh[n], acc[m][n], 0, 0, 0);
          acc[m][n] = __builtin_amdgcn_mfma_f32_16x16x32_f16(ah[m], bl[n], acc[m][n], 0, 0, 0);
        }
    }

    // fold: p = fl(fl(zn+en) - acc*2^-9); D-frag: row=(lane>>4)*4+r, col=lane&15
#pragma unroll
    for (int m = 0; m < 4; ++m) {
#pragma unroll
      for (int r = 0; r < 4; ++r) {
        int pt = m * 16 + hq * 4 + r;
        float zn = znb[pt];
        int c0i = k0 + w * 32 + lr;
        float t0 = zn + en_s[c0i];
        float p0 = t0 - acc[m][0][r] * 0.001953125f;
        float t1 = zn + en_s[c0i + 16];
        float p1 = t1 - acc[m][1][r] * 0.001953125f;
        float m1, m2; int i1;
        if (p1 < p0) { m1 = p1; i1 = c0i + 16; m2 = p0; }
        else         { m1 = p0; i1 = c0i;      m2 = p1; }
#pragma unroll
        for (int msk = 1; msk <= 8; msk <<= 1) {
          float om1 = __shfl_xor(m1, msk);
          float om2 = __shfl_xor(m2, msk);
          int   oi1 = __shfl_xor(i1, msk);
          if (om1 < m1 || (om1 == m1 && oi1 < i1)) {
            m2 = fminf(m1, om2); m1 = om1; i1 = oi1;
          } else {
            m2 = fminf(m2, om1);
          }
        }
        if (lr == 0) {
          float cm1 = rm1[w][pt];
          if (m1 < cm1 || (m1 == cm1 && i1 < ri1[w][pt])) {
            rm2[w][pt] = fminf(cm1, m2);
            rm1[w][pt] = m1; ri1[w][pt] = i1;
          } else {
            rm2[w][pt] = fminf(rm2[w][pt], m1);
          }
        }
      }
    }
  }
  __syncthreads();

  double dv = 0.0;
  if (tid < 64) {
    float m1 = rm1[0][tid], m2 = rm2[0][tid];
    int i1 = ri1[0][tid];
#pragma unroll
    for (int pq = 1; pq < 4; ++pq) {
      float a1 = rm1[pq][tid], a2 = rm2[pq][tid];
      int ai = ri1[pq][tid];
      if (a1 < m1 || (a1 == m1 && ai < i1)) {
        m2 = fminf(m1, a2); m1 = a1; i1 = ai;
      } else {
        m2 = fminf(m2, a1);
      }
    }
    int n = n0 + tid;
    out_idx[n] = (float)i1;
    if (m2 - m1 <= MARG) {
      int p = atomicAdd(flag_cnt, 1);
      if (p < NPTS) flags[p] = n;
    }
    dv = (double)m1;
  }
  if (tid < 64) {
#pragma unroll
    for (int msk = 1; msk < 64; msk <<= 1) dv += __shfl_xor(dv, msk);
    if (tid == 0) atomicAdd(loss_acc, dv);
  }
}

// exact numpy-fp32-chain re-decision for flagged points (round-2 semantics)
__global__ __launch_bounds__(256) void vq_recheck(
    const float* __restrict__ z, const float* __restrict__ emb,
    const float* __restrict__ enorm, const int* __restrict__ flag_cnt,
    const int* __restrict__ flags, float* __restrict__ out_idx) {
  __shared__ float zs[4][CH];
  __shared__ float znf[4];
  __shared__ float bm[256];
  __shared__ int   bi[256];
  int cnt = *flag_cnt; if (cnt > NPTS) cnt = NPTS;
  int t = threadIdx.x;
  for (int base = blockIdx.x * 4; base < cnt; base += gridDim.x * 4) {
#pragma unroll
    for (int q = 0; q < 4; ++q) {
      int ii = base + q; if (ii >= cnt) ii = cnt - 1;
      int n = flags[ii];
      int b = n / SPATIAL, s = n % SPATIAL;
      zs[q][t] = z[((size_t)b * CH + t) * SPATIAL + s];
    }
    __syncthreads();
    if (t < 4) {
      double sd = 0.0;
      for (int c = 0; c < CH; ++c) sd = fma((double)zs[t][c], (double)zs[t][c], sd);
      znf[t] = (float)sd;
    }
    __syncthreads();
    float best[4] = {1e30f, 1e30f, 1e30f, 1e30f};
    int besti[4] = {0, 0, 0, 0};
    for (int q = 0; q < 4; ++q) {
      int code = t + 256 * q;
      const float* er = emb + (size_t)code * CH;
      float g0 = 0.f, g1 = 0.f, g2 = 0.f, g3 = 0.f;
#pragma unroll 8
      for (int c = 0; c < CH; ++c) {
        float e = er[c];
        g0 = fmaf(zs[0][c], e, g0);
        g1 = fmaf(zs[1][c], e, g1);
        g2 = fmaf(zs[2][c], e, g2);
        g3 = fmaf(zs[3][c], e, g3);
      }
      float en = enorm[code];
      float d0 = (znf[0] + en) - 2.f * g0;
      float d1 = (znf[1] + en) - 2.f * g1;
      float d2 = (znf[2] + en) - 2.f * g2;
      float d3 = (znf[3] + en) - 2.f * g3;
      if (d0 < best[0]) { best[0] = d0; besti[0] = code; }
      if (d1 < best[1]) { best[1] = d1; besti[1] = code; }
      if (d2 < best[2]) { best[2] = d2; besti[2] = code; }
      if (d3 < best[3]) { best[3] = d3; besti[3] = code; }
    }
#pragma unroll
    for (int p = 0; p < 4; ++p) {
      bm[t] = best[p]; bi[t] = besti[p];
      __syncthreads();
      for (int off = 128; off > 0; off >>= 1) {
        if (t < off) {
          float ob = bm[t + off]; int oi = bi[t + off];
          if (ob < bm[t] || (ob == bm[t] && oi < bi[t])) { bm[t] = ob; bi[t] = oi; }
        }
        __syncthreads();
      }
      int ii = base + p;
      if (t == 0 && ii < cnt) out_idx[flags[ii]] = (float)bi[0];
      __syncthreads();
    }
  }
}

// z_q[b][c][s] = emb[idx][c]; finalize loss
__global__ __launch_bounds__(256) void vq_scatter(
    const float* __restrict__ emb, const float* __restrict__ out_idx,
    float* __restrict__ zq, const double* __restrict__ loss_acc,
    float* __restrict__ loss_out) {
  int c = blockIdx.y, b = blockIdx.z;
  int s = (blockIdx.x * 256 + threadIdx.x) * 4;
  int nb = b * SPATIAL + s;
  int i0 = (int)out_idx[nb + 0];
  int i1 = (int)out_idx[nb + 1];
  int i2 = (int)out_idx[nb + 2];
  int i3 = (int)out_idx[nb + 3];
  float4 o;
  o.x = emb[(size_t)i0 * CH + c];
  o.y = emb[(size_t)i1 * CH + c];
  o.z = emb[(size_t)i2 * CH + c];
  o.w = emb[(size_t)i3 * CH + c];
  *reinterpret_cast<float4*>(&zq[((size_t)(b * CH + c)) * SPATIAL + s]) = o;
  if (blockIdx.x == 0 && blockIdx.y == 0 && blockIdx.z == 0 && threadIdx.x == 0)
    loss_out[0] = (float)(loss_acc[0] * 1.25 / (double)ZQ_SIZE);
}

extern "C" void kernel_launch(void* const* d_in, const int* in_sizes, int n_in,
                              void* d_out, int out_size, void* d_ws, size_t ws_size,
                              hipStream_t stream) {
  const float* z   = (const float*)d_in[0];
  const float* emb = (const float*)d_in[1];
  float* out = (float*)d_out;
  char* ws = (char*)d_ws;

  double*   loss_acc = (double*)(ws + WS_LOSS);
  int*      flag_cnt = (int*)(ws + WS_CNT);
  float*    enorm    = (float*)(ws + WS_ENORM);
  _Float16* eh       = (_Float16*)(ws + WS_EH);
  _Float16* el       = (_Float16*)(ws + WS_EL);
  int*      flags    = (int*)(ws + WS_FLAGS);

  float* loss_out = out + ZQ_SIZE;
  float* out_idx  = out + ZQ_SIZE + 1;

  hipMemsetAsync(d_ws, 0, 16, stream);
  vq_prep<<<KCODES * CH / 256, 256, 0, stream>>>(emb, eh, el);
  vq_enorm<<<KCODES / 256, 256, 0, stream>>>(emb, enorm);
  vq_main<<<NPTS / 64, 256, 0, stream>>>(z, eh, el, enorm, out_idx,
                                         loss_acc, flag_cnt, flags);
  vq_recheck<<<512, 256, 0, stream>>>(z, emb, enorm, flag_cnt, flags, out_idx);
  vq_scatter<<<dim3(SPATIAL / 1024, CH, BATCH), 256, 0, stream>>>(
      emb, out_idx, out, loss_acc, loss_out);
}

// Round 4
// 623.889 us; speedup vs baseline: 2.5158x; 1.2390x over previous
//
#include <hip/hip_runtime.h>

#define SPATIAL 32768
#define BATCH   4
#define CH      256
#define KCODES  1024
#define NPTS    (BATCH*SPATIAL)          // 131072
#define ZQ_SIZE (BATCH*CH*SPATIAL)       // 33554432

// workspace layout (bytes)
#define WS_LOSS  0                        // double
#define WS_CNT   8                        // int
#define WS_ENORM 16                       // float[1024]
#define WS_EH    4112                     // _Float16[1024*256]
#define WS_EL    (WS_EH + KCODES*CH*2)
#define WS_FLAGS (WS_EL + KCODES*CH*2)    // int[NPTS]

#define MARG 1.5e-4f  // flag margin: covers split err + chain-vs-MFMA diff + 2 ulp(512)

typedef _Float16 f16x8 __attribute__((ext_vector_type(8)));
typedef float    f32x4 __attribute__((ext_vector_type(4)));

// split e*1024 into f16 hi/lo
__global__ __launch_bounds__(256) void vq_prep(const float* __restrict__ emb,
                                               _Float16* __restrict__ eh,
                                               _Float16* __restrict__ el) {
  int i = blockIdx.x * 256 + threadIdx.x;
  float es = emb[i] * 1024.0f;
  _Float16 h = (_Float16)es;
  eh[i] = h;
  el[i] = (_Float16)(es - (float)h);
}

__global__ __launch_bounds__(256) void vq_enorm(const float* __restrict__ emb,
                                                float* __restrict__ enorm) {
  int k = blockIdx.x * 256 + threadIdx.x;
  const float* e = emb + (size_t)k * CH;
  double s = 0.0;
#pragma unroll 8
  for (int c = 0; c < CH; ++c) s = fma((double)e[c], (double)e[c], s);
  enorm[k] = (float)s;
}

// 2048 blocks x 256 thr; block = 64 points x all 1024 codes via f16-split MFMA
__global__ __launch_bounds__(256) void vq_main(
    const float* __restrict__ z, const _Float16* __restrict__ eh_g,
    const _Float16* __restrict__ el_g, const float* __restrict__ enorm,
    float* __restrict__ out_idx, double* __restrict__ loss_acc,
    int* __restrict__ flag_cnt, int* __restrict__ flags) {
  // pad 264: row stride 132 dwords == 4 mod 32 -> b128 frag reads conflict-free
  __shared__ _Float16 zh[64][264];
  __shared__ _Float16 zl[64][264];
  __shared__ double   znp[4][64];
  __shared__ float    znb[64];
  __shared__ float rm1s[4][64];
  __shared__ float rm2s[4][64];
  __shared__ int   ri1s[4][64];

  int tid = threadIdx.x;
  int w = tid >> 6;          // wave 0..3
  int lane = tid & 63;
  int n0 = blockIdx.x * 64;
  int b = n0 / SPATIAL, s0 = n0 % SPATIAL;
  const float* zb = z + (size_t)b * CH * SPATIAL + s0;

  // stage z as f16 hi/lo, packed b128 writes (conflict-free); f64 zn partials
  {
    int pt = lane, crow = w;
    const float* zcol = zb + pt;
    double zacc = 0.0;
#pragma unroll
    for (int oct = 0; oct < 8; ++oct) {
      int c0 = crow * 64 + oct * 8;
      f16x8 h8, l8;
#pragma unroll
      for (int i = 0; i < 8; ++i) {
        float v = zcol[(size_t)(c0 + i) * SPATIAL];
        zacc = fma((double)v, (double)v, zacc);
        _Float16 h = (_Float16)v;
        h8[i] = h;
        l8[i] = (_Float16)(v - (float)h);
      }
      *(f16x8*)&zh[pt][c0] = h8;
      *(f16x8*)&zl[pt][c0] = l8;
    }
    znp[crow][pt] = zacc;
  }
  __syncthreads();
  if (tid < 64)
    znb[tid] = (float)(znp[0][tid] + znp[1][tid] + znp[2][tid] + znp[3][tid]);
  __syncthreads();

  int hq = lane >> 4;   // 0..3  (k-slice group)
  int lr = lane & 15;   // A-row / B-col selector

  // hoist enorm + zn into registers
  float en_reg[16];
#pragma unroll
  for (int kt = 0; kt < 8; ++kt) {
    en_reg[kt * 2]     = enorm[kt * 128 + w * 32 + lr];
    en_reg[kt * 2 + 1] = enorm[kt * 128 + w * 32 + lr + 16];
  }
  float znr[16];
#pragma unroll
  for (int m = 0; m < 4; ++m)
#pragma unroll
    for (int r = 0; r < 4; ++r)
      znr[m * 4 + r] = znb[m * 16 + hq * 4 + r];

  // per-thread running top-2 per row (all indices compile-time -> registers)
  float rm1[16], rm2[16];
  int   ri1[16];
#pragma unroll
  for (int q = 0; q < 16; ++q) { rm1[q] = 1e30f; rm2[q] = 1e30f; ri1[q] = 0; }

  for (int kt = 0; kt < 8; ++kt) {
    int k0 = kt * 128;
    f32x4 acc[4][2];
#pragma unroll
    for (int m = 0; m < 4; ++m)
#pragma unroll
      for (int n = 0; n < 2; ++n) acc[m][n] = (f32x4){0.f, 0.f, 0.f, 0.f};

#pragma unroll 2
    for (int cc = 0; cc < 8; ++cc) {
      int ca = cc * 32 + hq * 8;
      f16x8 ah[4], al[4], bh[2], bl[2];
#pragma unroll
      for (int m = 0; m < 4; ++m) {
        ah[m] = *(const f16x8*)&zh[m * 16 + lr][ca];
        al[m] = *(const f16x8*)&zl[m * 16 + lr][ca];
      }
#pragma unroll
      for (int n = 0; n < 2; ++n) {
        int code = k0 + w * 32 + n * 16 + lr;
        bh[n] = *(const f16x8*)&eh_g[(size_t)code * CH + ca];
        bl[n] = *(const f16x8*)&el_g[(size_t)code * CH + ca];
      }
#pragma unroll
      for (int m = 0; m < 4; ++m)
#pragma unroll
        for (int n = 0; n < 2; ++n) {
          acc[m][n] = __builtin_amdgcn_mfma_f32_16x16x32_f16(ah[m], bh[n], acc[m][n], 0, 0, 0);
          acc[m][n] = __builtin_amdgcn_mfma_f32_16x16x32_f16(al[m], bh[n], acc[m][n], 0, 0, 0);
          acc[m][n] = __builtin_amdgcn_mfma_f32_16x16x32_f16(ah[m], bl[n], acc[m][n], 0, 0, 0);
        }
    }

    // fold into per-thread top-2 (no cross-lane work here)
    float enA = en_reg[kt * 2], enB = en_reg[kt * 2 + 1];
    int c0i = k0 + w * 32 + lr;
#pragma unroll
    for (int m = 0; m < 4; ++m) {
#pragma unroll
      for (int r = 0; r < 4; ++r) {
        int q = m * 4 + r;
        float zn = znr[q];
        float p0 = (zn + enA) - acc[m][0][r] * 0x1p-9f;
        float p1 = (zn + enB) - acc[m][1][r] * 0x1p-9f;
        if (p0 < rm1[q]) { rm2[q] = rm1[q]; rm1[q] = p0; ri1[q] = c0i; }
        else             { rm2[q] = fminf(rm2[q], p0); }
        if (p1 < rm1[q]) { rm2[q] = rm1[q]; rm1[q] = p1; ri1[q] = c0i + 16; }
        else             { rm2[q] = fminf(rm2[q], p1); }
      }
    }
  }

  // one butterfly per row across the 16 lr-lanes
#pragma unroll
  for (int m = 0; m < 4; ++m) {
#pragma unroll
    for (int r = 0; r < 4; ++r) {
      int q = m * 4 + r;
      float m1 = rm1[q], m2 = rm2[q];
      int i1 = ri1[q];
#pragma unroll
      for (int msk = 1; msk <= 8; msk <<= 1) {
        float om1 = __shfl_xor(m1, msk);
        float om2 = __shfl_xor(m2, msk);
        int   oi1 = __shfl_xor(i1, msk);
        if (om1 < m1 || (om1 == m1 && oi1 < i1)) {
          m2 = fminf(m1, om2); m1 = om1; i1 = oi1;
        } else {
          m2 = fminf(m2, om1);
        }
      }
      if (lr == 0) {
        int pt = m * 16 + hq * 4 + r;
        rm1s[w][pt] = m1; rm2s[w][pt] = m2; ri1s[w][pt] = i1;
      }
    }
  }
  __syncthreads();

  double dv = 0.0;
  if (tid < 64) {
    float m1 = rm1s[0][tid], m2 = rm2s[0][tid];
    int i1 = ri1s[0][tid];
#pragma unroll
    for (int pq = 1; pq < 4; ++pq) {
      float a1 = rm1s[pq][tid], a2 = rm2s[pq][tid];
      int ai = ri1s[pq][tid];
      if (a1 < m1 || (a1 == m1 && ai < i1)) {
        m2 = fminf(m1, a2); m1 = a1; i1 = ai;
      } else {
        m2 = fminf(m2, a1);
      }
    }
    int n = n0 + tid;
    out_idx[n] = (float)i1;
    if (m2 - m1 <= MARG) {
      int p = atomicAdd(flag_cnt, 1);
      if (p < NPTS) flags[p] = n;
    }
    dv = (double)m1;
#pragma unroll
    for (int msk = 1; msk < 64; msk <<= 1) dv += __shfl_xor(dv, msk);
    if (tid == 0) atomicAdd(loss_acc, dv);
  }
}

// exact numpy-fp32-chain re-decision for flagged points
__global__ __launch_bounds__(256) void vq_recheck(
    const float* __restrict__ z, const float* __restrict__ emb,
    const float* __restrict__ enorm, const int* __restrict__ flag_cnt,
    const int* __restrict__ flags, float* __restrict__ out_idx) {
  __shared__ float zs[4][CH];
  __shared__ float znf[4];
  __shared__ float bm[256];
  __shared__ int   bi[256];
  int cnt = *flag_cnt; if (cnt > NPTS) cnt = NPTS;
  int t = threadIdx.x;
  for (int base = blockIdx.x * 4; base < cnt; base += gridDim.x * 4) {
#pragma unroll
    for (int q = 0; q < 4; ++q) {
      int ii = base + q; if (ii >= cnt) ii = cnt - 1;
      int n = flags[ii];
      int b = n / SPATIAL, s = n % SPATIAL;
      zs[q][t] = z[((size_t)b * CH + t) * SPATIAL + s];
    }
    __syncthreads();
    if (t < 4) {
      double sd = 0.0;
      for (int c = 0; c < CH; ++c) sd = fma((double)zs[t][c], (double)zs[t][c], sd);
      znf[t] = (float)sd;
    }
    __syncthreads();
    float best[4] = {1e30f, 1e30f, 1e30f, 1e30f};
    int besti[4] = {0, 0, 0, 0};
    for (int q = 0; q < 4; ++q) {
      int code = t + 256 * q;
      const float* er = emb + (size_t)code * CH;
      float g0 = 0.f, g1 = 0.f, g2 = 0.f, g3 = 0.f;
#pragma unroll 8
      for (int c = 0; c < CH; ++c) {
        float e = er[c];
        g0 = fmaf(zs[0][c], e, g0);
        g1 = fmaf(zs[1][c], e, g1);
        g2 = fmaf(zs[2][c], e, g2);
        g3 = fmaf(zs[3][c], e, g3);
      }
      float en = enorm[code];
      float d0 = (znf[0] + en) - 2.f * g0;
      float d1 = (znf[1] + en) - 2.f * g1;
      float d2 = (znf[2] + en) - 2.f * g2;
      float d3 = (znf[3] + en) - 2.f * g3;
      if (d0 < best[0]) { best[0] = d0; besti[0] = code; }
      if (d1 < best[1]) { best[1] = d1; besti[1] = code; }
      if (d2 < best[2]) { best[2] = d2; besti[2] = code; }
      if (d3 < best[3]) { best[3] = d3; besti[3] = code; }
    }
#pragma unroll
    for (int p = 0; p < 4; ++p) {
      bm[t] = best[p]; bi[t] = besti[p];
      __syncthreads();
      for (int off = 128; off > 0; off >>= 1) {
        if (t < off) {
          float ob = bm[t + off]; int oi = bi[t + off];
          if (ob < bm[t] || (ob == bm[t] && oi < bi[t])) { bm[t] = ob; bi[t] = oi; }
        }
        __syncthreads();
      }
      int ii = base + p;
      if (t == 0 && ii < cnt) out_idx[flags[ii]] = (float)bi[0];
      __syncthreads();
    }
  }
}

// z_q[b][c][s] = emb[idx][c]; finalize loss
__global__ __launch_bounds__(256) void vq_scatter(
    const float* __restrict__ emb, const float* __restrict__ out_idx,
    float* __restrict__ zq, const double* __restrict__ loss_acc,
    float* __restrict__ loss_out) {
  int c = blockIdx.y, b = blockIdx.z;
  int s = (blockIdx.x * 256 + threadIdx.x) * 4;
  int nb = b * SPATIAL + s;
  int i0 = (int)out_idx[nb + 0];
  int i1 = (int)out_idx[nb + 1];
  int i2 = (int)out_idx[nb + 2];
  int i3 = (int)out_idx[nb + 3];
  float4 o;
  o.x = emb[(size_t)i0 * CH + c];
  o.y = emb[(size_t)i1 * CH + c];
  o.z = emb[(size_t)i2 * CH + c];
  o.w = emb[(size_t)i3 * CH + c];
  *reinterpret_cast<float4*>(&zq[((size_t)(b * CH + c)) * SPATIAL + s]) = o;
  if (blockIdx.x == 0 && blockIdx.y == 0 && blockIdx.z == 0 && threadIdx.x == 0)
    loss_out[0] = (float)(loss_acc[0] * 1.25 / (double)ZQ_SIZE);
}

extern "C" void kernel_launch(void* const* d_in, const int* in_sizes, int n_in,
                              void* d_out, int out_size, void* d_ws, size_t ws_size,
                              hipStream_t stream) {
  const float* z   = (const float*)d_in[0];
  const float* emb = (const float*)d_in[1];
  float* out = (float*)d_out;
  char* ws = (char*)d_ws;

  double*   loss_acc = (double*)(ws + WS_LOSS);
  int*      flag_cnt = (int*)(ws + WS_CNT);
  float*    enorm    = (float*)(ws + WS_ENORM);
  _Float16* eh       = (_Float16*)(ws + WS_EH);
  _Float16* el       = (_Float16*)(ws + WS_EL);
  int*      flags    = (int*)(ws + WS_FLAGS);

  float* loss_out = out + ZQ_SIZE;
  float* out_idx  = out + ZQ_SIZE + 1;

  hipMemsetAsync(d_ws, 0, 16, stream);
  vq_prep<<<KCODES * CH / 256, 256, 0, stream>>>(emb, eh, el);
  vq_enorm<<<KCODES / 256, 256, 0, stream>>>(emb, enorm);
  vq_main<<<NPTS / 64, 256, 0, stream>>>(z, eh, el, enorm, out_idx,
                                         loss_acc, flag_cnt, flags);
  vq_recheck<<<512, 256, 0, stream>>>(z, emb, enorm, flag_cnt, flags, out_idx);
  vq_scatter<<<dim3(SPATIAL / 1024, CH, BATCH), 256, 0, stream>>>(
      emb, out_idx, out, loss_acc, loss_out);
}